// Round 4
// baseline (236.639 us; speedup 1.0000x reference)
//
#include <hip/hip_runtime.h>

// PCEN: x [32, 256, 4096] fp32. EMA over time per row, then
// out = sqrt(x / (m+eps)^0.98 + 2) - sqrt(2).
//
// Sync-free design: one WAVE per 1024-element chunk (4 waves/block = 1 row).
// Incoming carry is reconstructed from a redundant 256-element warm-up window
// (a^256 = 1.5e-3 -> truncation error ~1e-3 << 9.7e-2 threshold), so there is
// NO LDS, NO __syncthreads, NO cross-wave communication. Warm-up needs only a
// weighted wave reduction (6 shfl_xor); main chunk needs one 6-step wave scan.

constexpr int T_LEN = 4096;
constexpr int CHUNK = 1024;   // elements per wave
constexpr int WARM  = 256;    // warm-up window (256 = 64 lanes x 4)

constexpr float EPSF = 1e-6f;
constexpr float SF   = 0.025f;
constexpr float A1F  = 0.975f;

// exact powers of 0.975 via constexpr repeated squaring
constexpr double dA1   = 0.975;
constexpr double dA2   = dA1 * dA1;
constexpr double dA4   = dA2 * dA2;
constexpr double dA8   = dA4 * dA4;
constexpr double dA16  = dA8 * dA8;
constexpr double dA32  = dA16 * dA16;
constexpr double dA64  = dA32 * dA32;
constexpr double dA128 = dA64 * dA64;
constexpr double dA256 = dA128 * dA128;
constexpr double dA512 = dA256 * dA256;

__global__ __launch_bounds__(256, 8) void pcen_kernel(
    const float* __restrict__ x, float* __restrict__ out)
{
    const int tid  = threadIdx.x;
    const int lane = tid & 63;
    const int wave = tid >> 6;          // chunk index within row, 0..3
    const long long rbase = (long long)blockIdx.x * T_LEN;
    const int cbase = wave * CHUNK;     // chunk start within row

    const float4* __restrict__ px   = (const float4*)(x + rbase);
    float4* __restrict__       pout = (float4*)(out + rbase);

    // ---- issue all loads up front (5 independent float4s) ----
    const int f0 = (cbase >> 2) + lane * 4;   // lane owns elements [cbase+16*lane, +16)
    float4 v0 = px[f0 + 0];
    float4 v1 = px[f0 + 1];
    float4 v2 = px[f0 + 2];
    float4 v3 = px[f0 + 3];
    float4 wv = make_float4(0.f, 0.f, 0.f, 0.f);
    if (wave > 0)                              // wave-uniform branch
        wv = px[((cbase - WARM) >> 2) + lane]; // warm-up: lane -> float4 #lane

    // ---- warm-up: weighted reduction -> carry T at chunk start ----
    float T = 0.f;
    if (wave > 0) {
        float Lw = SF * wv.x;
        Lw = fmaf(A1F, Lw, SF * wv.y);
        Lw = fmaf(A1F, Lw, SF * wv.z);
        Lw = fmaf(A1F, Lw, SF * wv.w);
        // weight A4^(63-lane), exact from bits
        int e = 63 - lane;
        float f = 1.f;
        if (e & 1)  f *= (float)dA4;
        if (e & 2)  f *= (float)dA8;
        if (e & 4)  f *= (float)dA16;
        if (e & 8)  f *= (float)dA32;
        if (e & 16) f *= (float)dA64;
        if (e & 32) f *= (float)dA128;
        float vs = f * Lw;
        vs += __shfl_xor(vs, 1,  64);
        vs += __shfl_xor(vs, 2,  64);
        vs += __shfl_xor(vs, 4,  64);
        vs += __shfl_xor(vs, 8,  64);
        vs += __shfl_xor(vs, 16, 64);
        vs += __shfl_xor(vs, 32, 64);
        T = vs;
    }

    // ---- local scan over 16 elements -> segment total S ----
    float xv[16] = { v0.x, v0.y, v0.z, v0.w,
                     v1.x, v1.y, v1.z, v1.w,
                     v2.x, v2.y, v2.z, v2.w,
                     v3.x, v3.y, v3.z, v3.w };
    float S = 0.f;
#pragma unroll
    for (int k = 0; k < 16; ++k) S = fmaf(A1F, S, SF * xv[k]);

    // ---- wave-level inclusive scan of segment totals, coeff A16^offset ----
    float P = S, t;
    t = __shfl_up(P, 1,  64); if (lane >= 1)  P = fmaf((float)dA16,  t, P);
    t = __shfl_up(P, 2,  64); if (lane >= 2)  P = fmaf((float)dA32,  t, P);
    t = __shfl_up(P, 4,  64); if (lane >= 4)  P = fmaf((float)dA64,  t, P);
    t = __shfl_up(P, 8,  64); if (lane >= 8)  P = fmaf((float)dA128, t, P);
    t = __shfl_up(P, 16, 64); if (lane >= 16) P = fmaf((float)dA256, t, P);
    t = __shfl_up(P, 32, 64); if (lane >= 32) P = fmaf((float)dA512, t, P);

    // carry into lane's segment = P_{lane-1} + A16^lane * T
    float carry = __shfl_up(P, 1, 64);
    if (lane == 0) carry = 0.f;
    {
        int e = lane;
        float f = 1.f;
        if (e & 1)  f *= (float)dA16;
        if (e & 2)  f *= (float)dA32;
        if (e & 4)  f *= (float)dA64;
        if (e & 8)  f *= (float)dA128;
        if (e & 16) f *= (float)dA256;
        if (e & 32) f *= (float)dA512;
        carry = fmaf(f, T, carry);
    }

    // ---- recompute EMA with carry + fused epilogue, store per group ----
    const float SQRT_D = 1.41421356237309515f;  // sqrt(2.0)
    float m = carry;
#pragma unroll
    for (int g = 0; g < 4; ++g) {
        float4 r;
        float* rp = &r.x;
#pragma unroll
        for (int j = 0; j < 4; ++j) {
            float xx = xv[g * 4 + j];
            m = fmaf(A1F, m, SF * xx);
            // (m+eps)^-0.98 = exp2(-0.98 * log2(m+eps))
            float p = __builtin_amdgcn_exp2f(-0.98f * __builtin_amdgcn_logf(m + EPSF));
            rp[j] = __fsqrt_rn(fmaf(xx, p, 2.0f)) - SQRT_D;
        }
        pout[f0 + g] = r;
    }
}

extern "C" void kernel_launch(void* const* d_in, const int* in_sizes, int n_in,
                              void* d_out, int out_size, void* d_ws, size_t ws_size,
                              hipStream_t stream) {
    const float* x = (const float*)d_in[0];
    float* out = (float*)d_out;
    const int rows = in_sizes[0] / T_LEN;  // 32*256 = 8192 blocks, 1 row each
    pcen_kernel<<<dim3(rows), dim3(256), 0, stream>>>(x, out);
}